// Round 21
// baseline (222.144 us; speedup 1.0000x reference)
//
#include <hip/hip_runtime.h>
#include <math.h>

#define HH 28
#define VV 784
#define EE 1512
#define TT 25
#define M0C 0.05

// d_ws layout (bytes):
//   ORDER int32 [784*784] @ 0          (2458624)
//   D2S   f32   [784*784] @ 2458624    (2458624)
//   MT    f32   [784*128] @ 4917248    (401408)   transposed masses MT[v*128+b]
//   F     f32   [128*784] @ 5318656    (401408)

#define DECODE(idx, A, B)                                                  \
  {                                                                        \
    if ((idx) < 756) {                                                     \
      int i_ = (idx) / 27, j_ = (idx) - i_ * 27;                           \
      A = i_ * HH + j_; B = A + 1;                                         \
    } else {                                                               \
      int q_ = (idx) - 756;                                                \
      int i_ = q_ / HH, j_ = q_ - i_ * HH;                                 \
      A = i_ * HH + j_; B = A + HH;                                        \
    }                                                                      \
  }

// fused: blocks [0,784) sort one coord row (u32 integer-keyed); blocks [784,912) normalize one batch
__global__ __launch_bounds__(512) void k_pre(const float* __restrict__ x,
                                             int* __restrict__ ORDER, float* __restrict__ D2S,
                                             float* __restrict__ MT) {
  __shared__ unsigned keysU[1024];
  __shared__ double sred[8];
  __shared__ double Ssh;
  const int tid = threadIdx.x;
  if (blockIdx.x < VV) {
    const int v = blockIdx.x;
    const int i1 = v / HH, j1 = v % HH;
    const double step = 1.0 / 27.0;
    const double c0v = (i1 == 27) ? 0.0 : 1.0 - (double)i1 * step;
    const double c1v = (j1 == 27) ? 1.0 : (double)j1 * step;
    // integer key: s = di^2+dj^2 (monotone in f64 d2 across classes; within a
    // class all f32 d2 are equal so tie order is output-invariant)
    for (int u = tid; u < 1024; u += 512) {
      unsigned key = 0xFFFFFFFFu;
      if (u < VV) {
        int i2 = u / HH, j2 = u % HH;
        int di = i1 - i2, dj = j1 - j2;
        unsigned s = (unsigned)(di * di + dj * dj);
        key = (s << 10) | (unsigned)u;
      }
      keysU[u] = key;
    }
    __syncthreads();
    for (unsigned k = 2; k <= 1024; k <<= 1) {
      for (unsigned j = k >> 1; j; j >>= 1) {
        for (unsigned i = tid; i < 1024; i += 512) {
          unsigned l = i ^ j;
          if (l > i) {
            unsigned a = keysU[i], c = keysU[l];
            if ((a > c) == ((i & k) == 0)) { keysU[i] = c; keysU[l] = a; }
          }
        }
        __syncthreads();
      }
    }
    for (int u = tid; u < VV; u += 512) {
      int uu = (int)(keysU[u] & 1023u);
      ORDER[v * VV + u] = uu;
      int i2 = uu / HH, j2 = uu % HH;
      double c0u = (i2 == 27) ? 0.0 : 1.0 - (double)i2 * step;
      double c1u = (j2 == 27) ? 1.0 : (double)j2 * step;
      double dx = c0v - c0u, dy = c1v - c1u;
      D2S[v * VV + u] = (float)(dx * dx + dy * dy);
    }
  } else {
    const int b = blockIdx.x - VV;
    double s = 0.0;
    for (int i = tid; i < VV; i += 512) s += (double)x[b * VV + i];
    for (int off = 32; off; off >>= 1) s += __shfl_xor(s, off, 64);
    if ((tid & 63) == 0) sred[tid >> 6] = s;
    __syncthreads();
    if (tid == 0) {
      double S = 0.0;
      #pragma unroll
      for (int wv = 0; wv < 8; ++wv) S += sred[wv];
      Ssh = (S > 1e-12) ? S : 1e-12;
    }
    __syncthreads();
    double S = Ssh;
    for (int i = tid; i < VV; i += 512) MT[i * 128 + b] = (float)((double)x[b * VV + i] / S);
  }
}

// one block per vertex v; lane owns batch b; sequential k-walk with
// in-register prefix (reference semantics: take = min(mass, clamp(M0 - prefix)))
__global__ __launch_bounds__(128) void k_dtm(const float* __restrict__ MT, const int* __restrict__ ORDER,
                                             const float* __restrict__ D2S, float* __restrict__ F) {
  const int v = blockIdx.x;
  const int tid = threadIdx.x;  // 128 threads = 2 waves; b = tid
  __shared__ int ordS[VV];
  __shared__ float d2sS[VV];
  for (int k = tid; k < VV; k += 128) {
    ordS[k] = ORDER[v * VV + k];
    d2sS[k] = D2S[v * VV + k];
  }
  __syncthreads();
  float P = 0.0f, acc = 0.0f;
  for (int base = 0; base < VV; base += 16) {  // 784 = 49*16, no tail
    #pragma unroll
    for (int kk = 0; kk < 16; ++kk) {
      int k = base + kk;
      float mass = MT[ordS[k] * 128 + tid];  // coalesced 64x4B per wave
      float room = (float)M0C - P;
      room = room > 0.0f ? room : 0.0f;
      float take = mass < room ? mass : room;
      acc += take * d2sS[k];
      P += mass;
    }
    if (__all(P >= (float)M0C)) break;  // per-wave exit; clamp keeps exactness
  }
  F[tid * VV + v] = sqrtf(acc / (float)M0C + 1e-12f);
}

__global__ __launch_bounds__(1024) void k_main(const float* __restrict__ F,
                                               const float* __restrict__ w_topo, const float* __restrict__ b_topo,
                                               const float* __restrict__ w_fc, const float* __restrict__ b_fc,
                                               float* __restrict__ out) {
  const int b = blockIdx.x;
  const int tid = threadIdx.x;
  __shared__ float fv[VV];
  __shared__ unsigned long long keys[2048];
  __shared__ unsigned long long par64[VV];  // pack(f_root, root); depth<=1 invariant at batch entry
  __shared__ unsigned long long pairs[VV];  // (birth_bits<<32)|death_bits, positive persistence only
  __shared__ float feat[2 * TT];
  __shared__ float hbuf[100];
  __shared__ int cntS;
  for (int i = tid; i < VV; i += 1024) {
    float f = F[b * VV + i];
    fv[i] = f;
    par64[i] = ((unsigned long long)__float_as_uint(f) << 32) | (unsigned)i;
  }
  __syncthreads();
  // key: (w_bits<<32) | (isV<<20) | (aa<<10) | bb — low bits monotone in edge
  // index within each class, so ascending sort == stable argsort by (w, e).
  for (int e = tid; e < 2048; e += 1024) {
    unsigned long long key = 0xFFFFFFFF00000000ULL;  // sentinel: aa=bb=0 self-edge
    if (e < EE) {
      int aa, bb;
      DECODE(e, aa, bb);
      float w = fmaxf(fv[aa], fv[bb]);
      unsigned lo = ((e >= 756) ? (1u << 20) : 0u) | ((unsigned)aa << 10) | (unsigned)bb;
      key = ((unsigned long long)__float_as_uint(w) << 32) | lo;
    }
    keys[e] = key;
  }
  __syncthreads();
  for (unsigned k = 2; k <= 2048; k <<= 1) {
    for (unsigned j = k >> 1; j; j >>= 1) {
      for (unsigned i = tid; i < 2048; i += 1024) {
        unsigned l = i ^ j;
        if (l > i) {
          unsigned long long a = keys[i], c = keys[l];
          if ((a > c) == ((i & k) == 0)) { keys[i] = c; keys[l] = a; }
        }
      }
      __syncthreads();
    }
  }
  // ---- batched wave-parallel Kruskal elder-rule union-find (wave 0) ----
  // Round-20 form + scalar candB bit-test step guard: skipped steps are
  // ~3 SALU ops with NO dependence on patched state (candB is loop-invariant
  // SGPR). Stale candidates entering the body are naturally harmless:
  // young==oldv -> all patches value-identity; merge-record guarded by sdf.
  if (tid < 64) {
    const int lane = tid;
    const unsigned long long lbit = 1ULL << lane;
    int cnt = 0;
    int totalM = 0;
    unsigned long long K = keys[lane];
    for (int batch = 0; batch < 24; ++batch) {
      // prefetch next batch's key (max index 1599 < 2048: sentinel region, safe)
      unsigned long long Kn = keys[(batch + 1) * 64 + lane];
      unsigned lo = (unsigned)K;
      int aa = (int)((lo >> 10) & 1023), bb = (int)(lo & 1023);
      unsigned wbits = (unsigned)(K >> 32);
      // find: single packed read per endpoint (depth<=1 invariant)
      unsigned long long pka = par64[aa], pkb = par64[bb];
      unsigned ra = (unsigned)pka, rb = (unsigned)pkb;
      unsigned fa = (unsigned)(pka >> 32), fb = (unsigned)(pkb >> 32);
      unsigned long long candB = __ballot(ra != rb);
      if (candB) {
        bool rec = false;
        bool iMerged = false;
        unsigned long long pairv = 0;
        if (__popcll(candB) == 1) {
          // single candidate: no interaction possible; old root IS final
          if (ra != rb) {
            bool ya = (fa >= fb);  // young = a-side on ties (reference semantics)
            unsigned young = ya ? ra : rb;
            unsigned oldv = ya ? rb : ra;
            unsigned foldv = ya ? fb : fa;
            unsigned birth = ya ? fa : fb;
            par64[young] = ((unsigned long long)foldv << 32) | oldv;
            pairv = ((unsigned long long)birth << 32) | wbits;
            rec = (wbits > birth);
            iMerged = true;
          }
        } else {
          // static 64-step sweep, sorted (lane) order; scalar bit-test guard
          int merged = 0;
          unsigned young_w = 0;
          #pragma unroll 4
          for (int j = 0; j < 64; ++j) {
            if ((candB >> j) & 1ULL) {  // loop-invariant SGPR test: no readlane dep
              unsigned s_ra = (unsigned)__builtin_amdgcn_readlane((int)ra, j);
              unsigned s_rb = (unsigned)__builtin_amdgcn_readlane((int)rb, j);
              unsigned s_fa = (unsigned)__builtin_amdgcn_readlane((int)fa, j);
              unsigned s_fb = (unsigned)__builtin_amdgcn_readlane((int)fb, j);
              bool sdf = (s_ra != s_rb);  // stale check (body is no-op if stale)
              bool ya = (s_fa >= s_fb);   // young = a-side on ties
              unsigned young = ya ? s_ra : s_rb;
              unsigned oldv = ya ? s_rb : s_ra;
              unsigned foldv = ya ? s_fb : s_fa;
              unsigned birth = ya ? s_fa : s_fb;
              bool me = (lane == j) && sdf;
              merged = me ? 1 : merged;
              young_w = me ? young : young_w;
              pairv = me ? (((unsigned long long)birth << 32) | wbits) : pairv;
              // stale => young==oldv, foldv==f(young): patches are value-identity
              bool ma = (ra == young);
              ra = ma ? oldv : ra;
              fa = ma ? foldv : fa;
              bool mb2 = (rb == young);
              rb = mb2 ? oldv : rb;
              fb = mb2 ? foldv : fb;
            }
          }
          // merged lane's (fa,ra) are fully patched -> FINAL root pack.
          // Distinct youngs -> no collisions; dead roots point at final roots.
          if (merged) par64[young_w] = ((unsigned long long)fa << 32) | ra;
          rec = merged && ((unsigned)pairv > (unsigned)(pairv >> 32));
          iMerged = (merged != 0);
        }
        // record positive-persistence pairs only (zero tents are 0 in ref)
        unsigned long long recB = __ballot(rec);
        int rank = __popcll(recB & (lbit - 1ULL));
        if (rec) pairs[cnt + rank] = pairv;
        cnt += (int)__popcll(recB);
        totalM += (int)__popcll(__ballot(iMerged));
        // fixed one-pass halving repair (exact: depth<=2 before, <=1 after;
        // all concurrent writes to read-targets are value-preserving)
        {
          #pragma unroll
          for (int s = 0; s < 12; ++s) {
            unsigned long long p = par64[lane + 64 * s];
            unsigned long long q = par64[(unsigned)p];
            par64[lane + 64 * s] = q;
          }
          if (lane < 16) {
            unsigned long long p = par64[768 + lane];
            unsigned long long q = par64[(unsigned)p];
            par64[768 + lane] = q;
          }
        }
        if (totalM >= VV - 1) break;  // MST complete: nothing can merge later
      }
      K = Kn;
    }
    if (lane == 0) cntS = cnt;
  }
  __syncthreads();
  const int cnt = cntS;
  const int wid = tid >> 6, lane = tid & 63;
  // landscape: top-2 tents per t (ref's 1512-vector always contains zeros,
  // so init 0 == picking zero entries when fewer than 2 positive tents)
  for (int t = wid; t < TT; t += 16) {
    double tvd = (t == 24) ? 0.5 : (double)t * (0.5 / 24.0);
    float tv = (float)tvd;
    float m1 = 0.0f, m2 = 0.0f;
    for (int pidx = lane; pidx < cnt; pidx += 64) {
      unsigned long long pr = pairs[pidx];
      float pbv = __uint_as_float((unsigned)(pr >> 32));
      float pdv = __uint_as_float((unsigned)pr);
      float tent = fminf(tv - pbv, pdv - tv);
      tent = fmaxf(tent, 0.0f);
      if (tent > m1) { m2 = m1; m1 = tent; }
      else if (tent > m2) { m2 = tent; }
    }
    #pragma unroll
    for (int off = 32; off; off >>= 1) {
      float o1 = __shfl_xor(m1, off, 64);
      float o2 = __shfl_xor(m2, off, 64);
      float n1 = fmaxf(m1, o1);
      float n2 = fmaxf(fminf(m1, o1), fmaxf(m2, o2));
      m1 = n1; m2 = n2;
    }
    if (lane == 0) { feat[t] = m1; feat[TT + t] = m2; }
  }
  __syncthreads();
  // MLP: relu(feat @ w_topo + b_topo) @ w_fc + b_fc
  if (tid < 100) {
    double h = (double)b_topo[tid];
    for (int k2 = 0; k2 < 50; ++k2) h += (double)feat[k2] * (double)w_topo[k2 * 100 + tid];
    hbuf[tid] = (h > 0.0) ? (float)h : 0.0f;
  }
  __syncthreads();
  if (tid < 10) {
    double o = (double)b_fc[tid];
    for (int k2 = 0; k2 < 100; ++k2) o += (double)hbuf[k2] * (double)w_fc[k2 * 10 + tid];
    out[b * 10 + tid] = (float)o;
  }
}

extern "C" void kernel_launch(void* const* d_in, const int* in_sizes, int n_in,
                              void* d_out, int out_size, void* d_ws, size_t ws_size,
                              hipStream_t stream) {
  const float* x = (const float*)d_in[0];
  const float* w_topo = (const float*)d_in[1];
  const float* b_topo = (const float*)d_in[2];
  const float* w_fc = (const float*)d_in[3];
  const float* b_fc = (const float*)d_in[4];
  float* outp = (float*)d_out;
  char* ws = (char*)d_ws;
  int* ORDER = (int*)ws;
  float* D2S = (float*)(ws + 2458624);
  float* MT = (float*)(ws + 4917248);
  float* F = (float*)(ws + 5318656);

  hipLaunchKernelGGL(k_pre, dim3(VV + 128), dim3(512), 0, stream, x, ORDER, D2S, MT);
  hipLaunchKernelGGL(k_dtm, dim3(VV), dim3(128), 0, stream, MT, ORDER, D2S, F);
  hipLaunchKernelGGL(k_main, dim3(128), dim3(1024), 0, stream, F, w_topo, b_topo, w_fc, b_fc, outp);
}

// Round 22
// 175.373 us; speedup vs baseline: 1.2667x; 1.2667x over previous
//
#include <hip/hip_runtime.h>
#include <math.h>

#define HH 28
#define VV 784
#define EE 1512
#define TT 25
#define M0C 0.05

// d_ws layout (bytes):
//   ORDER int32 [784*784] @ 0          (2458624)
//   D2S   f32   [784*784] @ 2458624    (2458624)
//   MT    f32   [784*128] @ 4917248    (401408)   transposed masses MT[v*128+b]
//   F     f32   [128*784] @ 5318656    (401408)

#define DECODE(idx, A, B)                                                  \
  {                                                                        \
    if ((idx) < 756) {                                                     \
      int i_ = (idx) / 27, j_ = (idx) - i_ * 27;                           \
      A = i_ * HH + j_; B = A + 1;                                         \
    } else {                                                               \
      int q_ = (idx) - 756;                                                \
      int i_ = q_ / HH, j_ = q_ - i_ * HH;                                 \
      A = i_ * HH + j_; B = A + HH;                                        \
    }                                                                      \
  }

// fused: blocks [0,784) sort one coord row (u32 integer-keyed); blocks [784,912) normalize one batch
__global__ __launch_bounds__(512) void k_pre(const float* __restrict__ x,
                                             int* __restrict__ ORDER, float* __restrict__ D2S,
                                             float* __restrict__ MT) {
  __shared__ unsigned keysU[1024];
  __shared__ double sred[8];
  __shared__ double Ssh;
  const int tid = threadIdx.x;
  if (blockIdx.x < VV) {
    const int v = blockIdx.x;
    const int i1 = v / HH, j1 = v % HH;
    const double step = 1.0 / 27.0;
    const double c0v = (i1 == 27) ? 0.0 : 1.0 - (double)i1 * step;
    const double c1v = (j1 == 27) ? 1.0 : (double)j1 * step;
    // integer key: s = di^2+dj^2 (monotone in f64 d2 across classes; within a
    // class all f32 d2 are equal so tie order is output-invariant)
    for (int u = tid; u < 1024; u += 512) {
      unsigned key = 0xFFFFFFFFu;
      if (u < VV) {
        int i2 = u / HH, j2 = u % HH;
        int di = i1 - i2, dj = j1 - j2;
        unsigned s = (unsigned)(di * di + dj * dj);
        key = (s << 10) | (unsigned)u;
      }
      keysU[u] = key;
    }
    __syncthreads();
    for (unsigned k = 2; k <= 1024; k <<= 1) {
      for (unsigned j = k >> 1; j; j >>= 1) {
        for (unsigned i = tid; i < 1024; i += 512) {
          unsigned l = i ^ j;
          if (l > i) {
            unsigned a = keysU[i], c = keysU[l];
            if ((a > c) == ((i & k) == 0)) { keysU[i] = c; keysU[l] = a; }
          }
        }
        __syncthreads();
      }
    }
    for (int u = tid; u < VV; u += 512) {
      int uu = (int)(keysU[u] & 1023u);
      ORDER[v * VV + u] = uu;
      int i2 = uu / HH, j2 = uu % HH;
      double c0u = (i2 == 27) ? 0.0 : 1.0 - (double)i2 * step;
      double c1u = (j2 == 27) ? 1.0 : (double)j2 * step;
      double dx = c0v - c0u, dy = c1v - c1u;
      D2S[v * VV + u] = (float)(dx * dx + dy * dy);
    }
  } else {
    const int b = blockIdx.x - VV;
    double s = 0.0;
    for (int i = tid; i < VV; i += 512) s += (double)x[b * VV + i];
    for (int off = 32; off; off >>= 1) s += __shfl_xor(s, off, 64);
    if ((tid & 63) == 0) sred[tid >> 6] = s;
    __syncthreads();
    if (tid == 0) {
      double S = 0.0;
      #pragma unroll
      for (int wv = 0; wv < 8; ++wv) S += sred[wv];
      Ssh = (S > 1e-12) ? S : 1e-12;
    }
    __syncthreads();
    double S = Ssh;
    for (int i = tid; i < VV; i += 512) MT[i * 128 + b] = (float)((double)x[b * VV + i] / S);
  }
}

// one block per vertex v; lane owns batch b; sequential k-walk with
// in-register prefix (reference semantics: take = min(mass, clamp(M0 - prefix)))
__global__ __launch_bounds__(128) void k_dtm(const float* __restrict__ MT, const int* __restrict__ ORDER,
                                             const float* __restrict__ D2S, float* __restrict__ F) {
  const int v = blockIdx.x;
  const int tid = threadIdx.x;  // 128 threads = 2 waves; b = tid
  __shared__ int ordS[VV];
  __shared__ float d2sS[VV];
  for (int k = tid; k < VV; k += 128) {
    ordS[k] = ORDER[v * VV + k];
    d2sS[k] = D2S[v * VV + k];
  }
  __syncthreads();
  float P = 0.0f, acc = 0.0f;
  for (int base = 0; base < VV; base += 16) {  // 784 = 49*16, no tail
    #pragma unroll
    for (int kk = 0; kk < 16; ++kk) {
      int k = base + kk;
      float mass = MT[ordS[k] * 128 + tid];  // coalesced 64x4B per wave
      float room = (float)M0C - P;
      room = room > 0.0f ? room : 0.0f;
      float take = mass < room ? mass : room;
      acc += take * d2sS[k];
      P += mass;
    }
    if (__all(P >= (float)M0C)) break;  // per-wave exit; clamp keeps exactness
  }
  F[tid * VV + v] = sqrtf(acc / (float)M0C + 1e-12f);
}

__global__ __launch_bounds__(1024) void k_main(const float* __restrict__ F,
                                               const float* __restrict__ w_topo, const float* __restrict__ b_topo,
                                               const float* __restrict__ w_fc, const float* __restrict__ b_fc,
                                               float* __restrict__ out) {
  const int b = blockIdx.x;
  const int tid = threadIdx.x;
  __shared__ float fv[VV];
  __shared__ unsigned long long keys[2048];
  __shared__ unsigned long long par64[VV];  // pack(f_root, root); depth<=1 invariant at batch entry
  __shared__ unsigned long long pairs[VV];  // (birth_bits<<32)|death_bits, positive persistence only
  __shared__ float feat[2 * TT];
  __shared__ float hbuf[100];
  __shared__ int cntS;
  for (int i = tid; i < VV; i += 1024) {
    float f = F[b * VV + i];
    fv[i] = f;
    par64[i] = ((unsigned long long)__float_as_uint(f) << 32) | (unsigned)i;
  }
  __syncthreads();
  // key: (w_bits<<32) | (isV<<20) | (aa<<10) | bb — low bits monotone in edge
  // index within each class, so ascending sort == stable argsort by (w, e).
  for (int e = tid; e < 2048; e += 1024) {
    unsigned long long key = 0xFFFFFFFF00000000ULL;  // sentinel: aa=bb=0 self-edge
    if (e < EE) {
      int aa, bb;
      DECODE(e, aa, bb);
      float w = fmaxf(fv[aa], fv[bb]);
      unsigned lo = ((e >= 756) ? (1u << 20) : 0u) | ((unsigned)aa << 10) | (unsigned)bb;
      key = ((unsigned long long)__float_as_uint(w) << 32) | lo;
    }
    keys[e] = key;
  }
  __syncthreads();
  for (unsigned k = 2; k <= 2048; k <<= 1) {
    for (unsigned j = k >> 1; j; j >>= 1) {
      for (unsigned i = tid; i < 2048; i += 1024) {
        unsigned l = i ^ j;
        if (l > i) {
          unsigned long long a = keys[i], c = keys[l];
          if ((a > c) == ((i & k) == 0)) { keys[i] = c; keys[l] = a; }
        }
      }
      __syncthreads();
    }
  }
  // ---- batched wave-parallel Kruskal elder-rule union-find (wave 0) ----
  // Round-17/19 proven form: depth<=1 find (ONE ds_read_b64), uniform-branch
  // static sweep, final-root merge writes, fixed one-pass halving repair.
  // Early exit once all 783 merges are done (MST complete: candB==0 forever).
  if (tid < 64) {
    const int lane = tid;
    const unsigned long long lbit = 1ULL << lane;
    int cnt = 0;
    int totalM = 0;
    unsigned long long K = keys[lane];
    for (int batch = 0; batch < 24; ++batch) {
      // prefetch next batch's key (max index 1599 < 2048: sentinel region, safe)
      unsigned long long Kn = keys[(batch + 1) * 64 + lane];
      unsigned lo = (unsigned)K;
      int aa = (int)((lo >> 10) & 1023), bb = (int)(lo & 1023);
      unsigned wbits = (unsigned)(K >> 32);
      // find: single packed read per endpoint (depth<=1 invariant)
      unsigned long long pka = par64[aa], pkb = par64[bb];
      unsigned ra = (unsigned)pka, rb = (unsigned)pkb;
      unsigned fa = (unsigned)(pka >> 32), fb = (unsigned)(pkb >> 32);
      unsigned long long candB = __ballot(ra != rb);
      if (candB) {
        bool rec = false;
        bool iMerged = false;
        unsigned long long pairv = 0;
        if (__popcll(candB) == 1) {
          // single candidate: no interaction possible; old root IS final
          if (ra != rb) {
            bool ya = (fa >= fb);  // young = a-side on ties (reference semantics)
            unsigned young = ya ? ra : rb;
            unsigned oldv = ya ? rb : ra;
            unsigned foldv = ya ? fb : fa;
            unsigned birth = ya ? fa : fb;
            par64[young] = ((unsigned long long)foldv << 32) | oldv;
            pairv = ((unsigned long long)birth << 32) | wbits;
            rec = (wbits > birth);
            iMerged = true;
          }
        } else {
          // static 64-step sweep, sorted (lane) order, uniform in-step branch
          int merged = 0;
          unsigned young_w = 0;
          #pragma unroll 4
          for (int j = 0; j < 64; ++j) {
            unsigned s_ra = (unsigned)__builtin_amdgcn_readlane((int)ra, j);
            unsigned s_rb = (unsigned)__builtin_amdgcn_readlane((int)rb, j);
            if (s_ra != s_rb) {  // uniform (scalar) branch
              unsigned s_fa = (unsigned)__builtin_amdgcn_readlane((int)fa, j);
              unsigned s_fb = (unsigned)__builtin_amdgcn_readlane((int)fb, j);
              bool ya = (s_fa >= s_fb);  // young = a-side on ties
              unsigned young = ya ? s_ra : s_rb;
              unsigned oldv = ya ? s_rb : s_ra;
              unsigned foldv = ya ? s_fb : s_fa;
              unsigned birth = ya ? s_fa : s_fb;
              bool me = (lane == j);
              merged = me ? 1 : merged;
              young_w = me ? young : young_w;
              pairv = me ? (((unsigned long long)birth << 32) | wbits) : pairv;
              bool ma = (ra == young);
              ra = ma ? oldv : ra;
              fa = ma ? foldv : fa;
              bool mb2 = (rb == young);
              rb = mb2 ? oldv : rb;
              fb = mb2 ? foldv : fb;
            }
          }
          // merged lane's (fa,ra) are fully patched -> FINAL root pack.
          // Distinct youngs -> no collisions; dead roots point at final roots.
          if (merged) par64[young_w] = ((unsigned long long)fa << 32) | ra;
          rec = merged && ((unsigned)pairv > (unsigned)(pairv >> 32));
          iMerged = (merged != 0);
        }
        // record positive-persistence pairs only (zero tents are 0 in ref)
        unsigned long long recB = __ballot(rec);
        int rank = __popcll(recB & (lbit - 1ULL));
        if (rec) pairs[cnt + rank] = pairv;
        cnt += (int)__popcll(recB);
        totalM += (int)__popcll(__ballot(iMerged));
        // fixed one-pass halving repair (exact: depth<=2 before, <=1 after;
        // all concurrent writes to read-targets are value-preserving)
        {
          #pragma unroll
          for (int s = 0; s < 12; ++s) {
            unsigned long long p = par64[lane + 64 * s];
            unsigned long long q = par64[(unsigned)p];
            par64[lane + 64 * s] = q;
          }
          if (lane < 16) {
            unsigned long long p = par64[768 + lane];
            unsigned long long q = par64[(unsigned)p];
            par64[768 + lane] = q;
          }
        }
        if (totalM >= VV - 1) break;  // MST complete: nothing can merge later
      }
      K = Kn;
    }
    if (lane == 0) cntS = cnt;
  }
  __syncthreads();
  const int cnt = cntS;
  const int wid = tid >> 6, lane = tid & 63;
  // landscape: top-2 tents per t (ref's 1512-vector always contains zeros,
  // so init 0 == picking zero entries when fewer than 2 positive tents)
  for (int t = wid; t < TT; t += 16) {
    double tvd = (t == 24) ? 0.5 : (double)t * (0.5 / 24.0);
    float tv = (float)tvd;
    float m1 = 0.0f, m2 = 0.0f;
    for (int pidx = lane; pidx < cnt; pidx += 64) {
      unsigned long long pr = pairs[pidx];
      float pbv = __uint_as_float((unsigned)(pr >> 32));
      float pdv = __uint_as_float((unsigned)pr);
      float tent = fminf(tv - pbv, pdv - tv);
      tent = fmaxf(tent, 0.0f);
      if (tent > m1) { m2 = m1; m1 = tent; }
      else if (tent > m2) { m2 = tent; }
    }
    #pragma unroll
    for (int off = 32; off; off >>= 1) {
      float o1 = __shfl_xor(m1, off, 64);
      float o2 = __shfl_xor(m2, off, 64);
      float n1 = fmaxf(m1, o1);
      float n2 = fmaxf(fminf(m1, o1), fmaxf(m2, o2));
      m1 = n1; m2 = n2;
    }
    if (lane == 0) { feat[t] = m1; feat[TT + t] = m2; }
  }
  __syncthreads();
  // MLP: relu(feat @ w_topo + b_topo) @ w_fc + b_fc
  if (tid < 100) {
    double h = (double)b_topo[tid];
    for (int k2 = 0; k2 < 50; ++k2) h += (double)feat[k2] * (double)w_topo[k2 * 100 + tid];
    hbuf[tid] = (h > 0.0) ? (float)h : 0.0f;
  }
  __syncthreads();
  if (tid < 10) {
    double o = (double)b_fc[tid];
    for (int k2 = 0; k2 < 100; ++k2) o += (double)hbuf[k2] * (double)w_fc[k2 * 10 + tid];
    out[b * 10 + tid] = (float)o;
  }
}

extern "C" void kernel_launch(void* const* d_in, const int* in_sizes, int n_in,
                              void* d_out, int out_size, void* d_ws, size_t ws_size,
                              hipStream_t stream) {
  const float* x = (const float*)d_in[0];
  const float* w_topo = (const float*)d_in[1];
  const float* b_topo = (const float*)d_in[2];
  const float* w_fc = (const float*)d_in[3];
  const float* b_fc = (const float*)d_in[4];
  float* outp = (float*)d_out;
  char* ws = (char*)d_ws;
  int* ORDER = (int*)ws;
  float* D2S = (float*)(ws + 2458624);
  float* MT = (float*)(ws + 4917248);
  float* F = (float*)(ws + 5318656);

  hipLaunchKernelGGL(k_pre, dim3(VV + 128), dim3(512), 0, stream, x, ORDER, D2S, MT);
  hipLaunchKernelGGL(k_dtm, dim3(VV), dim3(128), 0, stream, MT, ORDER, D2S, F);
  hipLaunchKernelGGL(k_main, dim3(128), dim3(1024), 0, stream, F, w_topo, b_topo, w_fc, b_fc, outp);
}